// Round 5
// baseline (357.107 us; speedup 1.0000x reference)
//
#include <hip/hip_runtime.h>
#include <stdint.h>

// ---------------------------------------------------------------------------
// Fused LocalBranch: ResNetMLP (5x GEMM+LN) + per-graph distance softmax pool.
// R5: the MLP is row-parallel => split each graph into 2 blocks of 64 rows
//     (2048 blocks, wave tile 64x32, acc=32 regs/lane, LDS 37.9KB =>
//     4 blocks/CU, 32 waves/CU). Z (bf16) goes to d_ws; a second kernel does
//     gram+softmax+pool per graph. Weights stay frag-packed in global (L2).
//     R4 lesson: reg budget is unified (~512/SIMD incl AGPR); acc=64 made
//     2 blocks/CU impossible -- acc=32 is the structural fix.
// ---------------------------------------------------------------------------

typedef __attribute__((ext_vector_type(8))) short bf16x8;   // 8 bf16 = 4 VGPRs
typedef __attribute__((ext_vector_type(4))) float f32x4;

#define XB_STRIDE 264            // 64-row A-tile, 256+8 pad
#define ZB_STRIDE 136            // 128-row Z-tile, 128+8 pad

__device__ __forceinline__ unsigned short f2bf(float f) {
  unsigned int u = __builtin_bit_cast(unsigned int, f);
  u += 0x7fffu + ((u >> 16) & 1u);           // RNE
  return (unsigned short)(u >> 16);
}
__device__ __forceinline__ float bf2f(unsigned short h) {
  unsigned int u = ((unsigned int)h) << 16;
  return __builtin_bit_cast(float, u);
}
__device__ __forceinline__ f32x4 zero4() {
  f32x4 v; v.x = 0.f; v.y = 0.f; v.z = 0.f; v.w = 0.f; return v;
}

// ---------------------------------------------------------------------------
// Weight prep: fp32 row-major W[K][N] -> bf16 MFMA-fragment order:
//   frag f = kc*(N/16) + ntile  (kc = 32-wide K slab), 64 lanes x 8 elems:
//   lane reads B[n = ntile*16 + (lane&15)][k = kc*32 + (lane>>4)*8 + e].
// ws regions (bf16 elems): stem @0 (16384) ; blocks @16384,81920,147456 ;
// head @212992 ; Z buffer @262144 (1024*128*128).
// ---------------------------------------------------------------------------
__global__ void prep_weights(const float* __restrict__ Win, const float* __restrict__ Wb,
                             const float* __restrict__ Wout, unsigned short* __restrict__ ws) {
  int g = blockIdx.x * 256 + threadIdx.x;     // one 8-elem lane-slot per thread
  if (g >= 30720) return;
  const float* W; int N; int local;
  if (g < 2048) { W = Win; N = 256; local = g; }
  else if (g < 26624) {
    int i = g - 2048; int blk = i >> 13; local = i & 8191;
    W = Wb + blk * 65536; N = 256;
  } else { W = Wout; N = 128; local = g - 26624; }
  int f = local >> 6, lane = local & 63;
  int NTL = N >> 4;
  int kc = f / NTL, ntile = f - kc * NTL;
  int n = ntile * 16 + (lane & 15);
  int k0 = kc * 32 + (lane >> 4) * 8;
  unsigned short o[8];
#pragma unroll
  for (int e = 0; e < 8; ++e) o[e] = f2bf(W[(size_t)(k0 + e) * N + n]);
  *reinterpret_cast<uint4*>(ws + (size_t)g * 8) = *reinterpret_cast<uint4*>(o);
}

// ---------------------------------------------------------------------------
// One GEMM(+bias+LN+act+residual) layer over 64 rows. 8 waves split N:
// wave tile = 64 rows x (NT*16) cols (NT=2 -> N=256 ; NT=1 -> N=128).
// A from LDS (Xb), B-frags from global (frag-packed, L2-resident), software
// prefetch of next K-slab. MODE: 0 stem relu(ln) ; 1 residual ; 2 head ln.
// ---------------------------------------------------------------------------
template <int KL, int NT, int MODE>
__device__ __forceinline__ void layer_gemm(unsigned short* __restrict__ Xb,
                                           float* __restrict__ statS, float* __restrict__ statQ,
                                           const unsigned short* __restrict__ Wf,
                                           int wave, int lane,
                                           const float* __restrict__ bias,
                                           const float* __restrict__ gam,
                                           const float* __restrict__ bet) {
  const int q = lane >> 4;
  const int l16 = lane & 15;
  constexpr int KC = KL / 32;        // 32-wide K slabs (one MFMA k-step each)
  constexpr int NTL = NT * 8;        // 16-col tiles across full N
  constexpr int NCOLS = NT * 128;
  const int colbase = wave * (NT * 16);
  const unsigned short* Wl = Wf + lane * 8;

  f32x4 acc[4][NT];
#pragma unroll
  for (int mt = 0; mt < 4; ++mt)
#pragma unroll
    for (int nt = 0; nt < NT; ++nt) acc[mt][nt] = zero4();

  bf16x8 bcur[NT];
#pragma unroll
  for (int nt = 0; nt < NT; ++nt)    // prefetch slab 0 before the barrier
    bcur[nt] = *reinterpret_cast<const bf16x8*>(Wl + (size_t)(wave * NT + nt) * 512);

  __syncthreads();                   // Xb from previous layer ready
  for (int kc = 0; kc < KC; ++kc) {
    bf16x8 bnext[NT];
    if (kc + 1 < KC) {
#pragma unroll
      for (int nt = 0; nt < NT; ++nt)
        bnext[nt] = *reinterpret_cast<const bf16x8*>(
            Wl + (size_t)((kc + 1) * NTL + wave * NT + nt) * 512);
    }
    bf16x8 a[4];
    const int kk = kc * 32 + q * 8;
#pragma unroll
    for (int mt = 0; mt < 4; ++mt)
      a[mt] = *reinterpret_cast<const bf16x8*>(Xb + (16 * mt + l16) * XB_STRIDE + kk);
#pragma unroll
    for (int mt = 0; mt < 4; ++mt)
#pragma unroll
      for (int nt = 0; nt < NT; ++nt)
        acc[mt][nt] = __builtin_amdgcn_mfma_f32_16x16x32_bf16(a[mt], bcur[nt], acc[mt][nt], 0, 0, 0);
    if (kc + 1 < KC) {
#pragma unroll
      for (int nt = 0; nt < NT; ++nt) bcur[nt] = bnext[nt];
    }
  }
  // ---- epilogue: bias, cross-wave LN stats, normalize, act, residual, store
  float bcol[NT], gcol[NT], becol[NT];
#pragma unroll
  for (int nt = 0; nt < NT; ++nt) {
    int col = colbase + 16 * nt + l16;
    bcol[nt] = bias[col]; gcol[nt] = gam[col]; becol[nt] = bet[col];
  }
#pragma unroll
  for (int mt = 0; mt < 4; ++mt) {
#pragma unroll
    for (int nt = 0; nt < NT; ++nt) {
      acc[mt][nt].x += bcol[nt]; acc[mt][nt].y += bcol[nt];
      acc[mt][nt].z += bcol[nt]; acc[mt][nt].w += bcol[nt];
    }
    f32x4 s1 = acc[mt][0];
    f32x4 s2 = acc[mt][0] * acc[mt][0];
#pragma unroll
    for (int nt = 1; nt < NT; ++nt) { s1 += acc[mt][nt]; s2 += acc[mt][nt] * acc[mt][nt]; }
#pragma unroll
    for (int d = 1; d < 16; d <<= 1) {
#pragma unroll
      for (int r = 0; r < 4; ++r) {
        float t1 = s1[r]; t1 += __shfl_xor(t1, d); s1[r] = t1;
        float t2 = s2[r]; t2 += __shfl_xor(t2, d); s2[r] = t2;
      }
    }
    if (l16 == 0) {
#pragma unroll
      for (int r = 0; r < 4; ++r) {
        int row = 16 * mt + q * 4 + r;
        statS[row * 8 + wave] = s1[r];
        statQ[row * 8 + wave] = s2[r];
      }
    }
  }
  __syncthreads();                   // stats published; all A-reads of old Xb done
#pragma unroll
  for (int mt = 0; mt < 4; ++mt) {
#pragma unroll
    for (int r = 0; r < 4; ++r) {
      int row = 16 * mt + q * 4 + r;
      float S1 = 0.f, S2 = 0.f;
#pragma unroll
      for (int k = 0; k < 8; ++k) { S1 += statS[row * 8 + k]; S2 += statQ[row * 8 + k]; }
      float mu = S1 * (1.0f / NCOLS);
      float var = S2 * (1.0f / NCOLS) - mu * mu;
      float rstd = rsqrtf(var + 1e-5f);
#pragma unroll
      for (int nt = 0; nt < NT; ++nt) {
        int col = colbase + 16 * nt + l16;
        float y = (acc[mt][nt][r] - mu) * rstd * gcol[nt] + becol[nt];
        float xv;
        if constexpr (MODE == 0) { xv = fmaxf(y, 0.f); }
        else if constexpr (MODE == 1) {
          xv = bf2f(Xb[row * XB_STRIDE + col]) + fmaxf(y, 0.f);  // bf16 residual carry
        } else { xv = y; }
        Xb[row * XB_STRIDE + col] = f2bf(xv);
      }
    }
  }
}

// ---------------------------------------------------------------------------
// Kernel 1: ResNetMLP over 64 rows (half a graph). 2048 blocks x 512 thr.
// acc=32/lane => unified regs ~128/wave => 4 blocks/CU (LDS 37.9KB) possible.
// ---------------------------------------------------------------------------
__global__ __attribute__((amdgpu_flat_work_group_size(512, 512), amdgpu_waves_per_eu(4)))
void mlp_main(const float* __restrict__ H, const unsigned short* __restrict__ ws,
              const float* __restrict__ b_in, const float* __restrict__ g_in,
              const float* __restrict__ beta_in,
              const float* __restrict__ bb, const float* __restrict__ gb,
              const float* __restrict__ betab,
              const float* __restrict__ b_out, const float* __restrict__ g_out,
              const float* __restrict__ beta_out,
              unsigned short* __restrict__ Z) {
  __shared__ unsigned short Xb[64 * XB_STRIDE];
  __shared__ float statS[512], statQ[512];
  const int tid = threadIdx.x;
  const int g = blockIdx.x >> 1, h = blockIdx.x & 1;
  const int wave = tid >> 6, lane = tid & 63;

  // stage H rows [g*128 + h*64 .. +63], 64 cols -> Xb bf16
  {
    int row = tid >> 3, c0 = (tid & 7) * 8;
    const float4* hp = reinterpret_cast<const float4*>(
        H + ((size_t)g * 128 + h * 64 + row) * 64 + c0);
    float4 fa = hp[0], fb = hp[1];
    ushort4 o0, o1;
    o0.x = f2bf(fa.x); o0.y = f2bf(fa.y); o0.z = f2bf(fa.z); o0.w = f2bf(fa.w);
    o1.x = f2bf(fb.x); o1.y = f2bf(fb.y); o1.z = f2bf(fb.z); o1.w = f2bf(fb.w);
    *reinterpret_cast<ushort4*>(Xb + row * XB_STRIDE + c0) = o0;
    *reinterpret_cast<ushort4*>(Xb + row * XB_STRIDE + c0 + 4) = o1;
  }

  layer_gemm<64, 2, 0>(Xb, statS, statQ, ws,           wave, lane, b_in,     g_in,     beta_in);
  layer_gemm<256, 2, 1>(Xb, statS, statQ, ws + 16384,  wave, lane, bb,       gb,       betab);
  layer_gemm<256, 2, 1>(Xb, statS, statQ, ws + 81920,  wave, lane, bb + 256, gb + 256, betab + 256);
  layer_gemm<256, 2, 1>(Xb, statS, statQ, ws + 147456, wave, lane, bb + 512, gb + 512, betab + 512);
  layer_gemm<256, 1, 2>(Xb, statS, statQ, ws + 212992, wave, lane, b_out,    g_out,    beta_out);
  __syncthreads();                   // Z rows ready across waves

  // copy Z half-tile (64 rows x 128 cols bf16) -> global
  {
    int zr = tid >> 3, zc = (tid & 7) * 16;
    const uint4* src = reinterpret_cast<const uint4*>(Xb + zr * XB_STRIDE + zc);
    uint4* dst = reinterpret_cast<uint4*>(Z + ((size_t)g * 128 + h * 64 + zr) * 128 + zc);
    dst[0] = src[0]; dst[1] = src[1];
  }
}

// ---------------------------------------------------------------------------
// Kernel 2: per-graph gram + mean-distance + softmax + weighted pool.
// 1024 blocks x 512 thr; Z[g] (128x128 bf16) staged to LDS.
// ---------------------------------------------------------------------------
__global__ __attribute__((amdgpu_flat_work_group_size(512, 512)))
void pool_main(const unsigned short* __restrict__ Z, float* __restrict__ out) {
  __shared__ unsigned short Zb[128 * ZB_STRIDE];
  __shared__ float sqv[128], sm[128], smw[128];
  const int tid = threadIdx.x;
  const int g = blockIdx.x;
  const int wave = tid >> 6, lane = tid & 63;
  const int q = lane >> 4, l16 = lane & 15;

  {
    int zr = tid >> 2, zc = (tid & 3) * 32;
    const uint4* zp = reinterpret_cast<const uint4*>(Z + ((size_t)g * 128 + zr) * 128 + zc);
    uint4* zd = reinterpret_cast<uint4*>(Zb + zr * ZB_STRIDE + zc);
    zd[0] = zp[0]; zd[1] = zp[1]; zd[2] = zp[2]; zd[3] = zp[3];
  }
  __syncthreads();

  // gram G = Z Z^T : wave owns 16 rows x 128 cols
  f32x4 g2[8];
#pragma unroll
  for (int nt = 0; nt < 8; ++nt) g2[nt] = zero4();
#pragma unroll
  for (int ks = 0; ks < 4; ++ks) {
    int kk = ks * 32 + q * 8;
    bf16x8 a = *reinterpret_cast<const bf16x8*>(Zb + (16 * wave + l16) * ZB_STRIDE + kk);
#pragma unroll
    for (int nt = 0; nt < 8; ++nt) {
      bf16x8 bfr = *reinterpret_cast<const bf16x8*>(Zb + (16 * nt + l16) * ZB_STRIDE + kk);
      g2[nt] = __builtin_amdgcn_mfma_f32_16x16x32_bf16(a, bfr, g2[nt], 0, 0, 0);
    }
  }
  // publish sq_i = G_ii (diag) so d_ii == sqrt(1e-12) exactly like ref
  if ((l16 >> 2) == q) {
#pragma unroll
    for (int nt = 0; nt < 8; ++nt)
      if (nt == wave) {
#pragma unroll
        for (int r = 0; r < 4; ++r)
          if ((l16 & 3) == r) sqv[16 * wave + l16] = g2[nt][r];
      }
  }
  __syncthreads();
  // distances and s_i = mean_j d_ij
  float sqi[4];
#pragma unroll
  for (int r = 0; r < 4; ++r) sqi[r] = sqv[16 * wave + q * 4 + r];
  float sp[4] = {0.f, 0.f, 0.f, 0.f};
#pragma unroll
  for (int nt = 0; nt < 8; ++nt) {
    float sqj = sqv[16 * nt + l16];
#pragma unroll
    for (int r = 0; r < 4; ++r) {
      float d2 = sqi[r] + sqj - 2.0f * g2[nt][r];
      sp[r] += sqrtf(fmaxf(d2, 0.f) + 1e-12f);
    }
  }
#pragma unroll
  for (int d = 1; d < 16; d <<= 1) {
#pragma unroll
    for (int r = 0; r < 4; ++r) { float t = sp[r]; t += __shfl_xor(t, d); sp[r] = t; }
  }
  if (l16 == 0) {
#pragma unroll
    for (int r = 0; r < 4; ++r) sm[16 * wave + q * 4 + r] = sp[r] * (1.0f / 128.0f);
  }
  __syncthreads();
  // softmax(s/TAU) by wave 0 (1/TAU = 4)
  if (wave == 0) {
    float l0 = sm[lane] * 4.0f;
    float l1 = sm[lane + 64] * 4.0f;
    float mx = fmaxf(l0, l1);
#pragma unroll
    for (int d = 1; d < 64; d <<= 1) mx = fmaxf(mx, __shfl_xor(mx, d));
    float e0 = __expf(l0 - mx), e1 = __expf(l1 - mx);
    float ss = e0 + e1;
#pragma unroll
    for (int d = 1; d < 64; d <<= 1) ss += __shfl_xor(ss, d);
    float inv = 1.0f / ss;
    float w0 = e0 * inv, w1 = e1 * inv;
    smw[lane] = w0;
    smw[lane + 64] = w1;
    out[131072 + g * 128 + lane] = w0;
    out[131072 + g * 128 + 64 + lane] = w1;
  }
  __syncthreads();
  // v_loc = sum_i w_i * Z[i,:]
  {
    int c = 16 * wave + l16;
    float acv = 0.f;
#pragma unroll
    for (int i0 = 0; i0 < 32; ++i0) {
      int i = q * 32 + i0;
      acv += smw[i] * bf2f(Zb[i * ZB_STRIDE + c]);
    }
    acv += __shfl_xor(acv, 16);
    acv += __shfl_xor(acv, 32);
    if (q == 0) out[g * 128 + c] = acv;
  }
}

// ---------------------------------------------------------------------------
extern "C" void kernel_launch(void* const* d_in, const int* in_sizes, int n_in,
                              void* d_out, int out_size, void* d_ws, size_t ws_size,
                              hipStream_t stream) {
  (void)in_sizes; (void)n_in; (void)out_size; (void)ws_size;
  const float* H        = (const float*)d_in[0];
  // d_in[1] = batch_ptr (uniform 128/graph, unused)
  const float* W_in     = (const float*)d_in[2];
  const float* b_in     = (const float*)d_in[3];
  const float* g_in     = (const float*)d_in[4];
  const float* beta_in  = (const float*)d_in[5];
  const float* Wb       = (const float*)d_in[6];
  const float* bb       = (const float*)d_in[7];
  const float* gb       = (const float*)d_in[8];
  const float* betab    = (const float*)d_in[9];
  const float* W_out    = (const float*)d_in[10];
  const float* b_out    = (const float*)d_in[11];
  const float* g_out    = (const float*)d_in[12];
  const float* beta_out = (const float*)d_in[13];
  float* out = (float*)d_out;
  unsigned short* ws = (unsigned short*)d_ws;
  unsigned short* Z = ws + 262144;      // 1024*128*128 bf16 = 33.5 MB

  prep_weights<<<120, 256, 0, stream>>>(W_in, Wb, W_out, ws);
  mlp_main<<<2048, 512, 0, stream>>>(H, ws, b_in, g_in, beta_in,
                                     bb, gb, betab, b_out, g_out, beta_out, Z);
  pool_main<<<1024, 512, 0, stream>>>(Z, out);
}

// Round 6
// 290.827 us; speedup vs baseline: 1.2279x; 1.2279x over previous
//
#include <hip/hip_runtime.h>
#include <stdint.h>

// ---------------------------------------------------------------------------
// Fused LocalBranch: ResNetMLP (5x GEMM+LN) + per-graph distance softmax pool.
// R6: two-phase LN epilogue through a second LDS buffer Yb:
//     phase A: acc+bias -> bf16 -> Yb (scatter, C-layout)
//     phase B: row-parallel re-read (8 thr/row, b128), shfl-reduce stats,
//              normalize+residual+store to Xb.
//     Kills R5's statS[row*8+k] pattern (4-way bank conflict x 256 reads/thr/
//     layer, 1.43e7 conflict cycles) and cuts live regs so the 128-unified
//     cap at waves_per_eu(4) holds without spill (R5: 56MB scratch traffic).
// ---------------------------------------------------------------------------

typedef __attribute__((ext_vector_type(8))) short bf16x8;   // 8 bf16 = 4 VGPRs
typedef __attribute__((ext_vector_type(4))) float f32x4;

#define XB_STRIDE 264            // 256+8 pad; even bank spread for b128 frag reads
#define ZB_STRIDE 136            // pool Z tile 128+8

__device__ __forceinline__ unsigned short f2bf(float f) {
  unsigned int u = __builtin_bit_cast(unsigned int, f);
  u += 0x7fffu + ((u >> 16) & 1u);           // RNE
  return (unsigned short)(u >> 16);
}
__device__ __forceinline__ float bf2f(unsigned short h) {
  unsigned int u = ((unsigned int)h) << 16;
  return __builtin_bit_cast(float, u);
}
__device__ __forceinline__ f32x4 zero4() {
  f32x4 v; v.x = 0.f; v.y = 0.f; v.z = 0.f; v.w = 0.f; return v;
}

// ---------------------------------------------------------------------------
// Weight prep: fp32 row-major W[K][N] -> bf16 MFMA-fragment order:
//   frag f = kc*(N/16) + ntile  (kc = 32-wide K slab), 64 lanes x 8 elems:
//   lane reads B[n = ntile*16 + (lane&15)][k = kc*32 + (lane>>4)*8 + e].
// ws regions (bf16 elems): stem @0 ; blocks @16384,81920,147456 ; head @212992 ;
// Z buffer @262144 (1024*128*128).
// ---------------------------------------------------------------------------
__global__ void prep_weights(const float* __restrict__ Win, const float* __restrict__ Wb,
                             const float* __restrict__ Wout, unsigned short* __restrict__ ws) {
  int g = blockIdx.x * 256 + threadIdx.x;     // one 8-elem lane-slot per thread
  if (g >= 30720) return;
  const float* W; int N; int local;
  if (g < 2048) { W = Win; N = 256; local = g; }
  else if (g < 26624) {
    int i = g - 2048; int blk = i >> 13; local = i & 8191;
    W = Wb + blk * 65536; N = 256;
  } else { W = Wout; N = 128; local = g - 26624; }
  int f = local >> 6, lane = local & 63;
  int NTL = N >> 4;
  int kc = f / NTL, ntile = f - kc * NTL;
  int n = ntile * 16 + (lane & 15);
  int k0 = kc * 32 + (lane >> 4) * 8;
  unsigned short o[8];
#pragma unroll
  for (int e = 0; e < 8; ++e) o[e] = f2bf(W[(size_t)(k0 + e) * N + n]);
  *reinterpret_cast<uint4*>(ws + (size_t)g * 8) = *reinterpret_cast<uint4*>(o);
}

// ---------------------------------------------------------------------------
// One GEMM layer over 64 rows. 8 waves split N; wave tile 64 x (16*NT).
// N=256 -> NT=2 ; N=128 -> NT=1. A from LDS Xb, B-frags from global (L2).
// MODE: 0 stem x=relu(ln(y)) ; 1 residual x=Xb+relu(ln(y)) ; 2 head z=ln(y).
// ---------------------------------------------------------------------------
template <int KL, int N, int MODE>
__device__ __forceinline__ void layer_gemm(unsigned short* __restrict__ Xb,
                                           unsigned short* __restrict__ Yb,
                                           const unsigned short* __restrict__ Wf,
                                           int tid, int wave, int lane,
                                           const float* __restrict__ bias,
                                           const float* __restrict__ gam,
                                           const float* __restrict__ bet) {
  constexpr int NT = N / 128;        // frags per wave per k-slab
  constexpr int NTL = N / 16;        // 16-col tiles across N
  constexpr int KC = KL / 32;        // 32-wide K slabs
  constexpr int CPT = N / 8;         // cols per thread in phase B
  const int q = lane >> 4;
  const int l16 = lane & 15;
  const int colbase = wave * (16 * NT);
  const unsigned short* Wl = Wf + lane * 8;

  f32x4 acc[4][NT];
#pragma unroll
  for (int mt = 0; mt < 4; ++mt)
#pragma unroll
    for (int nt = 0; nt < NT; ++nt) acc[mt][nt] = zero4();

  bf16x8 bcur[NT];
#pragma unroll
  for (int nt = 0; nt < NT; ++nt)    // prefetch slab 0 before the barrier
    bcur[nt] = *reinterpret_cast<const bf16x8*>(Wl + (size_t)(wave * NT + nt) * 512);

  __syncthreads();                   // Xb from previous layer ready
  for (int kc = 0; kc < KC; ++kc) {
    bf16x8 bnext[NT];
    if (kc + 1 < KC) {
#pragma unroll
      for (int nt = 0; nt < NT; ++nt)
        bnext[nt] = *reinterpret_cast<const bf16x8*>(
            Wl + (size_t)((kc + 1) * NTL + wave * NT + nt) * 512);
    }
    const int kk = kc * 32 + q * 8;
#pragma unroll
    for (int mt = 0; mt < 4; ++mt) {
      bf16x8 a = *reinterpret_cast<const bf16x8*>(Xb + (16 * mt + l16) * XB_STRIDE + kk);
#pragma unroll
      for (int nt = 0; nt < NT; ++nt)
        acc[mt][nt] = __builtin_amdgcn_mfma_f32_16x16x32_bf16(a, bcur[nt], acc[mt][nt], 0, 0, 0);
    }
    if (kc + 1 < KC) {
#pragma unroll
      for (int nt = 0; nt < NT; ++nt) bcur[nt] = bnext[nt];
    }
  }

  // ---- phase A: + bias, bf16, scatter to Yb (C-layout slots)
#pragma unroll
  for (int nt = 0; nt < NT; ++nt) {
    const int col = colbase + 16 * nt + l16;
    const float bc = bias[col];
#pragma unroll
    for (int mt = 0; mt < 4; ++mt) {
#pragma unroll
      for (int r = 0; r < 4; ++r)
        Yb[(16 * mt + q * 4 + r) * XB_STRIDE + col] = f2bf(acc[mt][nt][r] + bc);
    }
  }
  __syncthreads();                   // Yb complete (also: all K-loop Xb reads done)

  // ---- phase B: row-parallel LN + act + residual -> Xb
  const int row = tid >> 3;
  const int c0 = (tid & 7) * CPT;
  bf16x8 yv[CPT / 8];
#pragma unroll
  for (int j = 0; j < CPT / 8; ++j)
    yv[j] = *reinterpret_cast<const bf16x8*>(Yb + row * XB_STRIDE + c0 + 8 * j);
  float s1 = 0.f, s2 = 0.f;
#pragma unroll
  for (int j = 0; j < CPT / 8; ++j)
#pragma unroll
    for (int e = 0; e < 8; ++e) {
      float v = bf2f((unsigned short)yv[j][e]);
      s1 += v; s2 += v * v;
    }
  s1 += __shfl_xor(s1, 1); s2 += __shfl_xor(s2, 1);
  s1 += __shfl_xor(s1, 2); s2 += __shfl_xor(s2, 2);
  s1 += __shfl_xor(s1, 4); s2 += __shfl_xor(s2, 4);
  const float mu = s1 * (1.0f / N);
  const float var = s2 * (1.0f / N) - mu * mu;
  const float rstd = rsqrtf(var + 1e-5f);
#pragma unroll
  for (int j = 0; j < CPT / 8; ++j) {
    float ga[8], be[8];
    *reinterpret_cast<float4*>(ga) = *reinterpret_cast<const float4*>(gam + c0 + 8 * j);
    *reinterpret_cast<float4*>(ga + 4) = *reinterpret_cast<const float4*>(gam + c0 + 8 * j + 4);
    *reinterpret_cast<float4*>(be) = *reinterpret_cast<const float4*>(bet + c0 + 8 * j);
    *reinterpret_cast<float4*>(be + 4) = *reinterpret_cast<const float4*>(bet + c0 + 8 * j + 4);
    bf16x8 rv;
    if constexpr (MODE == 1)
      rv = *reinterpret_cast<const bf16x8*>(Xb + row * XB_STRIDE + c0 + 8 * j);
    unsigned short o[8];
#pragma unroll
    for (int e = 0; e < 8; ++e) {
      float y = bf2f((unsigned short)yv[j][e]);
      float z = (y - mu) * rstd * ga[e] + be[e];
      float xv;
      if constexpr (MODE == 0) xv = fmaxf(z, 0.f);
      else if constexpr (MODE == 1) xv = bf2f((unsigned short)rv[e]) + fmaxf(z, 0.f);
      else xv = z;
      o[e] = f2bf(xv);
    }
    *reinterpret_cast<uint4*>(Xb + row * XB_STRIDE + c0 + 8 * j) = *reinterpret_cast<uint4*>(o);
  }
  // next layer's post-prefetch barrier separates these Xb writes from a-reads
}

// ---------------------------------------------------------------------------
// Kernel 1: ResNetMLP over 64 rows (half a graph). 2048 blocks x 512 thr.
// LDS 67.6 KB -> 2 blocks/CU ; waves_per_eu(4) -> 128 unified regs/wave.
// ---------------------------------------------------------------------------
__global__ __attribute__((amdgpu_flat_work_group_size(512, 512), amdgpu_waves_per_eu(4)))
void mlp_main(const float* __restrict__ H, const unsigned short* __restrict__ ws,
              const float* __restrict__ b_in, const float* __restrict__ g_in,
              const float* __restrict__ beta_in,
              const float* __restrict__ bb, const float* __restrict__ gb,
              const float* __restrict__ betab,
              const float* __restrict__ b_out, const float* __restrict__ g_out,
              const float* __restrict__ beta_out,
              unsigned short* __restrict__ Z) {
  __shared__ unsigned short Xb[64 * XB_STRIDE];
  __shared__ unsigned short Yb[64 * XB_STRIDE];
  const int tid = threadIdx.x;
  const int g = blockIdx.x >> 1, h = blockIdx.x & 1;
  const int wave = tid >> 6, lane = tid & 63;

  // stage H rows [g*128 + h*64 .. +63], 64 cols -> Xb bf16
  {
    int row = tid >> 3, c0 = (tid & 7) * 8;
    const float4* hp = reinterpret_cast<const float4*>(
        H + ((size_t)g * 128 + h * 64 + row) * 64 + c0);
    float4 fa = hp[0], fb = hp[1];
    ushort4 o0, o1;
    o0.x = f2bf(fa.x); o0.y = f2bf(fa.y); o0.z = f2bf(fa.z); o0.w = f2bf(fa.w);
    o1.x = f2bf(fb.x); o1.y = f2bf(fb.y); o1.z = f2bf(fb.z); o1.w = f2bf(fb.w);
    *reinterpret_cast<ushort4*>(Xb + row * XB_STRIDE + c0) = o0;
    *reinterpret_cast<ushort4*>(Xb + row * XB_STRIDE + c0 + 4) = o1;
  }

  layer_gemm<64, 256, 0>(Xb, Yb, ws,           tid, wave, lane, b_in,     g_in,     beta_in);
  layer_gemm<256, 256, 1>(Xb, Yb, ws + 16384,  tid, wave, lane, bb,       gb,       betab);
  layer_gemm<256, 256, 1>(Xb, Yb, ws + 81920,  tid, wave, lane, bb + 256, gb + 256, betab + 256);
  layer_gemm<256, 256, 1>(Xb, Yb, ws + 147456, tid, wave, lane, bb + 512, gb + 512, betab + 512);
  layer_gemm<256, 128, 2>(Xb, Yb, ws + 212992, tid, wave, lane, b_out,    g_out,    beta_out);

  // copy Z half-tile (64 rows x 128 cols bf16) -> global.
  // Head phase B wrote exactly these slots with the same thread mapping
  // (row = tid>>3, cols (tid&7)*16..+15) => no barrier needed.
  {
    int zr = tid >> 3, zc = (tid & 7) * 16;
    const uint4* src = reinterpret_cast<const uint4*>(Xb + zr * XB_STRIDE + zc);
    uint4* dst = reinterpret_cast<uint4*>(Z + ((size_t)g * 128 + h * 64 + zr) * 128 + zc);
    dst[0] = src[0]; dst[1] = src[1];
  }
}

// ---------------------------------------------------------------------------
// Kernel 2: per-graph gram + mean-distance + softmax + weighted pool.
// 1024 blocks x 512 thr; Z[g] (128x128 bf16) staged to LDS.
// ---------------------------------------------------------------------------
__global__ __attribute__((amdgpu_flat_work_group_size(512, 512)))
void pool_main(const unsigned short* __restrict__ Z, float* __restrict__ out) {
  __shared__ unsigned short Zb[128 * ZB_STRIDE];
  __shared__ float sqv[128], sm[128], smw[128];
  const int tid = threadIdx.x;
  const int g = blockIdx.x;
  const int wave = tid >> 6, lane = tid & 63;
  const int q = lane >> 4, l16 = lane & 15;

  {
    int zr = tid >> 2, zc = (tid & 3) * 32;
    const uint4* zp = reinterpret_cast<const uint4*>(Z + ((size_t)g * 128 + zr) * 128 + zc);
    uint4* zd = reinterpret_cast<uint4*>(Zb + zr * ZB_STRIDE + zc);
    zd[0] = zp[0]; zd[1] = zp[1]; zd[2] = zp[2]; zd[3] = zp[3];
  }
  __syncthreads();

  // gram G = Z Z^T : wave owns 16 rows x 128 cols
  f32x4 g2[8];
#pragma unroll
  for (int nt = 0; nt < 8; ++nt) g2[nt] = zero4();
#pragma unroll
  for (int ks = 0; ks < 4; ++ks) {
    int kk = ks * 32 + q * 8;
    bf16x8 a = *reinterpret_cast<const bf16x8*>(Zb + (16 * wave + l16) * ZB_STRIDE + kk);
#pragma unroll
    for (int nt = 0; nt < 8; ++nt) {
      bf16x8 bfr = *reinterpret_cast<const bf16x8*>(Zb + (16 * nt + l16) * ZB_STRIDE + kk);
      g2[nt] = __builtin_amdgcn_mfma_f32_16x16x32_bf16(a, bfr, g2[nt], 0, 0, 0);
    }
  }
  // publish sq_i = G_ii (diag) so d_ii == sqrt(1e-12) exactly like ref
  if ((l16 >> 2) == q) {
#pragma unroll
    for (int nt = 0; nt < 8; ++nt)
      if (nt == wave) {
#pragma unroll
        for (int r = 0; r < 4; ++r)
          if ((l16 & 3) == r) sqv[16 * wave + l16] = g2[nt][r];
      }
  }
  __syncthreads();
  // distances and s_i = mean_j d_ij
  float sqi[4];
#pragma unroll
  for (int r = 0; r < 4; ++r) sqi[r] = sqv[16 * wave + q * 4 + r];
  float sp[4] = {0.f, 0.f, 0.f, 0.f};
#pragma unroll
  for (int nt = 0; nt < 8; ++nt) {
    float sqj = sqv[16 * nt + l16];
#pragma unroll
    for (int r = 0; r < 4; ++r) {
      float d2 = sqi[r] + sqj - 2.0f * g2[nt][r];
      sp[r] += sqrtf(fmaxf(d2, 0.f) + 1e-12f);
    }
  }
#pragma unroll
  for (int d = 1; d < 16; d <<= 1) {
#pragma unroll
    for (int r = 0; r < 4; ++r) { float t = sp[r]; t += __shfl_xor(t, d); sp[r] = t; }
  }
  if (l16 == 0) {
#pragma unroll
    for (int r = 0; r < 4; ++r) sm[16 * wave + q * 4 + r] = sp[r] * (1.0f / 128.0f);
  }
  __syncthreads();
  // softmax(s/TAU) by wave 0 (1/TAU = 4)
  if (wave == 0) {
    float l0 = sm[lane] * 4.0f;
    float l1 = sm[lane + 64] * 4.0f;
    float mx = fmaxf(l0, l1);
#pragma unroll
    for (int d = 1; d < 64; d <<= 1) mx = fmaxf(mx, __shfl_xor(mx, d));
    float e0 = __expf(l0 - mx), e1 = __expf(l1 - mx);
    float ss = e0 + e1;
#pragma unroll
    for (int d = 1; d < 64; d <<= 1) ss += __shfl_xor(ss, d);
    float inv = 1.0f / ss;
    float w0 = e0 * inv, w1 = e1 * inv;
    smw[lane] = w0;
    smw[lane + 64] = w1;
    out[131072 + g * 128 + lane] = w0;
    out[131072 + g * 128 + 64 + lane] = w1;
  }
  __syncthreads();
  // v_loc = sum_i w_i * Z[i,:]
  {
    int c = 16 * wave + l16;
    float acv = 0.f;
#pragma unroll
    for (int i0 = 0; i0 < 32; ++i0) {
      int i = q * 32 + i0;
      acv += smw[i] * bf2f(Zb[i * ZB_STRIDE + c]);
    }
    acv += __shfl_xor(acv, 16);
    acv += __shfl_xor(acv, 32);
    if (q == 0) out[g * 128 + c] = acv;
  }
}

// ---------------------------------------------------------------------------
extern "C" void kernel_launch(void* const* d_in, const int* in_sizes, int n_in,
                              void* d_out, int out_size, void* d_ws, size_t ws_size,
                              hipStream_t stream) {
  (void)in_sizes; (void)n_in; (void)out_size; (void)ws_size;
  const float* H        = (const float*)d_in[0];
  // d_in[1] = batch_ptr (uniform 128/graph, unused)
  const float* W_in     = (const float*)d_in[2];
  const float* b_in     = (const float*)d_in[3];
  const float* g_in     = (const float*)d_in[4];
  const float* beta_in  = (const float*)d_in[5];
  const float* Wb       = (const float*)d_in[6];
  const float* bb       = (const float*)d_in[7];
  const float* gb       = (const float*)d_in[8];
  const float* betab    = (const float*)d_in[9];
  const float* W_out    = (const float*)d_in[10];
  const float* b_out    = (const float*)d_in[11];
  const float* g_out    = (const float*)d_in[12];
  const float* beta_out = (const float*)d_in[13];
  float* out = (float*)d_out;
  unsigned short* ws = (unsigned short*)d_ws;
  unsigned short* Z = ws + 262144;      // 1024*128*128 bf16 = 33.5 MB

  prep_weights<<<120, 256, 0, stream>>>(W_in, Wb, W_out, ws);
  mlp_main<<<2048, 512, 0, stream>>>(H, ws, b_in, g_in, beta_in,
                                     bb, gb, betab, b_out, g_out, beta_out, Z);
  pool_main<<<1024, 512, 0, stream>>>(Z, out);
}

// Round 7
// 251.126 us; speedup vs baseline: 1.4220x; 1.1581x over previous
//
#include <hip/hip_runtime.h>
#include <stdint.h>

// ---------------------------------------------------------------------------
// Fused LocalBranch: ResNetMLP (5x GEMM+LN) + per-graph distance softmax pool.
// R7: quarter-graph blocks (4096 x 512thr, 32 rows). Wave tile 32x32 ->
//     acc=16 regs, 16 epilogue values/thread, LDS 19.3KB -> ~3 blocks/CU.
//     Epilogue: DPP-fused stat reduction (v_add_f32_dpp x4), conflict-free
//     interleaved stats LDS + (mu,rstd) table, residual in registers,
//     pair-packed b32 Xb writes (v_perm) instead of 4-way-conflicted b16
//     scatter. Yb round-trip deleted.
// ---------------------------------------------------------------------------

typedef __attribute__((ext_vector_type(8))) short bf16x8;   // 8 bf16 = 4 VGPRs
typedef __attribute__((ext_vector_type(4))) float f32x4;

#define XB_STRIDE 264            // 256+8 pad (elems)
#define ZB_STRIDE 136            // pool Z tile 128+8

__device__ __forceinline__ unsigned int rne16(float f) {
  unsigned int u = __builtin_bit_cast(unsigned int, f);
  return u + 0x7fffu + ((u >> 16) & 1u);     // RNE bf16 in high 16 bits
}
__device__ __forceinline__ unsigned short f2bf(float f) {
  return (unsigned short)(rne16(f) >> 16);
}
__device__ __forceinline__ float bf2f(unsigned short h) {
  unsigned int u = ((unsigned int)h) << 16;
  return __builtin_bit_cast(float, u);
}
__device__ __forceinline__ f32x4 zero4() {
  f32x4 v; v.x = 0.f; v.y = 0.f; v.z = 0.f; v.w = 0.f; return v;
}
// pack own bf16 (low) + lane^1 partner bf16 (high); valid on even l16 lanes
__device__ __forceinline__ unsigned int pack_pair(float v) {
  unsigned int t = rne16(v);
  unsigned int tp = (unsigned int)__builtin_amdgcn_update_dpp(
      0, (int)t, 0xB1, 0xF, 0xF, true);                 // quad_perm xor1
  return __builtin_amdgcn_perm(tp, t, 0x07060302);
}
template <int CTRL>
__device__ __forceinline__ float dpp_add(float v) {
  int p = __builtin_amdgcn_update_dpp(0, __builtin_bit_cast(int, v),
                                      CTRL, 0xF, 0xF, true);
  return v + __builtin_bit_cast(float, p);
}
__device__ __forceinline__ float red16(float v) {  // sum over 16-lane group
  v = dpp_add<0xB1>(v);    // xor1  (quad_perm 1,0,3,2)
  v = dpp_add<0x4E>(v);    // xor2  (quad_perm 2,3,0,1)
  v = dpp_add<0x141>(v);   // row_half_mirror (quad<->quad within oct)
  v = dpp_add<0x140>(v);   // row_mirror      (oct<->oct within 16)
  return v;
}

// ---------------------------------------------------------------------------
// Weight prep: fp32 row-major W[K][N] -> bf16 MFMA-fragment order:
//   frag f = kc*(N/16) + ntile (kc = 32-wide K slab); 64 lanes x 8 elems:
//   lane reads B[n = ntile*16 + (lane&15)][k = kc*32 + (lane>>4)*8 + e].
// ws regions (bf16 elems): stem @0 ; blocks @16384,81920,147456 ; head @212992 ;
// Z buffer @262144 (1024*128*128).
// ---------------------------------------------------------------------------
__global__ void prep_weights(const float* __restrict__ Win, const float* __restrict__ Wb,
                             const float* __restrict__ Wout, unsigned short* __restrict__ ws) {
  int g = blockIdx.x * 256 + threadIdx.x;
  if (g >= 30720) return;
  const float* W; int N; int local;
  if (g < 2048) { W = Win; N = 256; local = g; }
  else if (g < 26624) {
    int i = g - 2048; int blk = i >> 13; local = i & 8191;
    W = Wb + blk * 65536; N = 256;
  } else { W = Wout; N = 128; local = g - 26624; }
  int f = local >> 6, lane = local & 63;
  int NTL = N >> 4;
  int kc = f / NTL, ntile = f - kc * NTL;
  int n = ntile * 16 + (lane & 15);
  int k0 = kc * 32 + (lane >> 4) * 8;
  unsigned short o[8];
#pragma unroll
  for (int e = 0; e < 8; ++e) o[e] = f2bf(W[(size_t)(k0 + e) * N + n]);
  *reinterpret_cast<uint4*>(ws + (size_t)g * 8) = *reinterpret_cast<uint4*>(o);
}

// ---------------------------------------------------------------------------
// One GEMM layer over 32 rows. 8 waves split N (wave tile 32 x 16*NT).
// A from LDS Xb, B-frags from global (frag-packed, L2). MODE: 0 stem, 1 resid
// (register carry), 2 head. 3 barriers/layer.
// ---------------------------------------------------------------------------
template <int KL, int N, int MODE>
__device__ __forceinline__ void layer(unsigned short* __restrict__ Xb,
                                      float* __restrict__ statQ, float* __restrict__ muR,
                                      const unsigned short* __restrict__ Wf,
                                      int tid, int wave, int lane,
                                      const float* __restrict__ bias,
                                      const float* __restrict__ gam,
                                      const float* __restrict__ bet,
                                      f32x4 (&xprev)[2][2]) {
  constexpr int NT = N / 128;        // 2 for N=256, 1 for N=128
  constexpr int NTL = N / 16;        // 16-col tiles across N
  constexpr int KC = KL / 32;        // 32-wide K slabs
  const int q = lane >> 4, l16 = lane & 15;
  const int colbase = wave * 16 * NT;
  const unsigned short* Wl = Wf + lane * 8;

  float bcol[NT], gcol[NT], becol[NT];
#pragma unroll
  for (int nt = 0; nt < NT; ++nt) {
    int col = colbase + 16 * nt + l16;
    bcol[nt] = bias[col]; gcol[nt] = gam[col]; becol[nt] = bet[col];
  }
  f32x4 acc[2][NT];
#pragma unroll
  for (int mt = 0; mt < 2; ++mt)
#pragma unroll
    for (int nt = 0; nt < NT; ++nt) acc[mt][nt] = zero4();

  bf16x8 bcur[NT];
#pragma unroll
  for (int nt = 0; nt < NT; ++nt)
    bcur[nt] = *reinterpret_cast<const bf16x8*>(Wl + (size_t)(wave * NT + nt) * 512);

  __syncthreads();                   // B1: Xb from prev layer ready
#pragma unroll
  for (int kc = 0; kc < KC; ++kc) {
    bf16x8 bnext[NT];
    if (kc + 1 < KC) {
#pragma unroll
      for (int nt = 0; nt < NT; ++nt)
        bnext[nt] = *reinterpret_cast<const bf16x8*>(
            Wl + (size_t)((kc + 1) * NTL + wave * NT + nt) * 512);
    }
    const int kk = kc * 32 + q * 8;
    bf16x8 a0 = *reinterpret_cast<const bf16x8*>(Xb + l16 * XB_STRIDE + kk);
    bf16x8 a1 = *reinterpret_cast<const bf16x8*>(Xb + (16 + l16) * XB_STRIDE + kk);
#pragma unroll
    for (int nt = 0; nt < NT; ++nt)
      acc[0][nt] = __builtin_amdgcn_mfma_f32_16x16x32_bf16(a0, bcur[nt], acc[0][nt], 0, 0, 0);
#pragma unroll
    for (int nt = 0; nt < NT; ++nt)
      acc[1][nt] = __builtin_amdgcn_mfma_f32_16x16x32_bf16(a1, bcur[nt], acc[1][nt], 0, 0, 0);
    if (kc + 1 < KC) {
#pragma unroll
      for (int nt = 0; nt < NT; ++nt) bcur[nt] = bnext[nt];
    }
  }

  // ---- bias + per-row stats (DPP reduce over the 16 l16 lanes)
#pragma unroll
  for (int mt = 0; mt < 2; ++mt) {
#pragma unroll
    for (int nt = 0; nt < NT; ++nt) {
      acc[mt][nt].x += bcol[nt]; acc[mt][nt].y += bcol[nt];
      acc[mt][nt].z += bcol[nt]; acc[mt][nt].w += bcol[nt];
    }
    f32x4 s1 = acc[mt][0];
    f32x4 s2 = acc[mt][0] * acc[mt][0];
    if constexpr (NT == 2) { s1 += acc[mt][1]; s2 += acc[mt][1] * acc[mt][1]; }
#pragma unroll
    for (int r = 0; r < 4; ++r) { s1[r] = red16(s1[r]); s2[r] = red16(s2[r]); }
    if (l16 == 0) {                  // rows 16mt+4q+r; interleave (s1,s2)
      float* sp = statQ + wave * 68 + mt * 32 + q * 8;
      f32x4 v0, v1;
      v0.x = s1.x; v0.y = s2.x; v0.z = s1.y; v0.w = s2.y;
      v1.x = s1.z; v1.y = s2.z; v1.z = s1.w; v1.w = s2.w;
      *reinterpret_cast<f32x4*>(sp) = v0;
      *reinterpret_cast<f32x4*>(sp + 4) = v1;
    }
  }
  __syncthreads();                   // B2: stats published
  if (tid < 32) {                    // per-row cross-wave reduce -> (mu,rstd)
    float S1 = 0.f, S2 = 0.f;
#pragma unroll
    for (int w = 0; w < 8; ++w) {
      float2 v = *reinterpret_cast<const float2*>(statQ + w * 68 + 2 * tid);
      S1 += v.x; S2 += v.y;
    }
    float mu = S1 * (1.0f / N);
    float var = S2 * (1.0f / N) - mu * mu;
    float rstd = rsqrtf(var + 1e-5f);
    float2 o; o.x = mu; o.y = rstd;
    *reinterpret_cast<float2*>(muR + 2 * tid) = o;
  }
  __syncthreads();                   // B3: (mu,rstd) ready
  unsigned int* Xw = reinterpret_cast<unsigned int*>(Xb);
#pragma unroll
  for (int mt = 0; mt < 2; ++mt)
#pragma unroll
    for (int r = 0; r < 4; ++r) {
      const int row = 16 * mt + 4 * q + r;
      float2 m = *reinterpret_cast<const float2*>(muR + 2 * row);  // broadcast
      const float nmr = -m.x * m.y;
#pragma unroll
      for (int nt = 0; nt < NT; ++nt) {
        float z = __builtin_fmaf(acc[mt][nt][r], m.y, nmr);        // (y-mu)*rstd
        float o = __builtin_fmaf(z, gcol[nt], becol[nt]);
        float xv;
        if constexpr (MODE == 0) { xv = fmaxf(o, 0.f); xprev[mt][nt][r] = xv; }
        else if constexpr (MODE == 1) {
          xv = xprev[mt][nt][r] + fmaxf(o, 0.f); xprev[mt][nt][r] = xv;
        } else { xv = o; }
        unsigned int pk = pack_pair(xv);
        if ((l16 & 1) == 0)          // even lane writes the (col,col+1) dword
          Xw[row * 132 + ((colbase + 16 * nt + l16) >> 1)] = pk;
      }
    }
}

// ---------------------------------------------------------------------------
// Kernel 1: ResNetMLP over 32 rows (quarter graph). 4096 blocks x 512 thr.
// ---------------------------------------------------------------------------
__global__ __attribute__((amdgpu_flat_work_group_size(512, 512), amdgpu_waves_per_eu(4)))
void mlp_main(const float* __restrict__ H, const unsigned short* __restrict__ ws,
              const float* __restrict__ b_in, const float* __restrict__ g_in,
              const float* __restrict__ beta_in,
              const float* __restrict__ bb, const float* __restrict__ gb,
              const float* __restrict__ betab,
              const float* __restrict__ b_out, const float* __restrict__ g_out,
              const float* __restrict__ beta_out,
              unsigned short* __restrict__ Z) {
  __shared__ __attribute__((aligned(16))) unsigned short Xb[32 * XB_STRIDE];
  __shared__ __attribute__((aligned(16))) float statQ[8 * 68];
  __shared__ __attribute__((aligned(16))) float muR[64];
  const int tid = threadIdx.x;
  const int wave = tid >> 6, lane = tid & 63;

  // stage H rows [b*32 .. +31], 64 cols -> Xb bf16 (pair-packed b64 stores)
  {
    int row = tid >> 4, c4 = (tid & 15) * 4;
    float4 f = *reinterpret_cast<const float4*>(
        H + ((size_t)blockIdx.x * 32 + row) * 64 + c4);
    unsigned int t0 = rne16(f.x), t1 = rne16(f.y), t2 = rne16(f.z), t3 = rne16(f.w);
    uint2 o;
    o.x = __builtin_amdgcn_perm(t1, t0, 0x07060302);
    o.y = __builtin_amdgcn_perm(t3, t2, 0x07060302);
    *reinterpret_cast<uint2*>(Xb + row * XB_STRIDE + c4) = o;
  }

  f32x4 xprev[2][2];
  layer<64, 256, 0>(Xb, statQ, muR, ws,           tid, wave, lane, b_in,     g_in,     beta_in,  xprev);
  layer<256, 256, 1>(Xb, statQ, muR, ws + 16384,  tid, wave, lane, bb,       gb,       betab,    xprev);
  layer<256, 256, 1>(Xb, statQ, muR, ws + 81920,  tid, wave, lane, bb + 256, gb + 256, betab + 256, xprev);
  layer<256, 256, 1>(Xb, statQ, muR, ws + 147456, tid, wave, lane, bb + 512, gb + 512, betab + 512, xprev);
  layer<256, 128, 2>(Xb, statQ, muR, ws + 212992, tid, wave, lane, b_out,    g_out,    beta_out, xprev);
  __syncthreads();                   // head Xb writes complete

  // coalesced copy Z quarter-tile (32 rows x 128 cols bf16) -> global
  {
    int row = tid >> 4, c8 = (tid & 15) * 8;
    uint4 v = *reinterpret_cast<const uint4*>(Xb + row * XB_STRIDE + c8);
    *reinterpret_cast<uint4*>(Z + ((size_t)blockIdx.x * 32 + row) * 128 + c8) = v;
  }
}

// ---------------------------------------------------------------------------
// Kernel 2: per-graph gram + mean-distance + softmax + weighted pool.
// 1024 blocks x 512 thr; Z[g] (128x128 bf16) staged to LDS.
// ---------------------------------------------------------------------------
__global__ __attribute__((amdgpu_flat_work_group_size(512, 512)))
void pool_main(const unsigned short* __restrict__ Z, float* __restrict__ out) {
  __shared__ unsigned short Zb[128 * ZB_STRIDE];
  __shared__ float sqv[128], sm[128], smw[128];
  const int tid = threadIdx.x;
  const int g = blockIdx.x;
  const int wave = tid >> 6, lane = tid & 63;
  const int q = lane >> 4, l16 = lane & 15;

  {
    int zr = tid >> 2, zc = (tid & 3) * 32;
    const uint4* zp = reinterpret_cast<const uint4*>(Z + ((size_t)g * 128 + zr) * 128 + zc);
    uint4* zd = reinterpret_cast<uint4*>(Zb + zr * ZB_STRIDE + zc);
    zd[0] = zp[0]; zd[1] = zp[1]; zd[2] = zp[2]; zd[3] = zp[3];
  }
  __syncthreads();

  // gram G = Z Z^T : wave owns 16 rows x 128 cols
  f32x4 g2[8];
#pragma unroll
  for (int nt = 0; nt < 8; ++nt) g2[nt] = zero4();
#pragma unroll
  for (int ks = 0; ks < 4; ++ks) {
    int kk = ks * 32 + q * 8;
    bf16x8 a = *reinterpret_cast<const bf16x8*>(Zb + (16 * wave + l16) * ZB_STRIDE + kk);
#pragma unroll
    for (int nt = 0; nt < 8; ++nt) {
      bf16x8 bfr = *reinterpret_cast<const bf16x8*>(Zb + (16 * nt + l16) * ZB_STRIDE + kk);
      g2[nt] = __builtin_amdgcn_mfma_f32_16x16x32_bf16(a, bfr, g2[nt], 0, 0, 0);
    }
  }
  // publish sq_i = G_ii (diag) so d_ii == sqrt(1e-12) exactly like ref
  if ((l16 >> 2) == q) {
#pragma unroll
    for (int nt = 0; nt < 8; ++nt)
      if (nt == wave) {
#pragma unroll
        for (int r = 0; r < 4; ++r)
          if ((l16 & 3) == r) sqv[16 * wave + l16] = g2[nt][r];
      }
  }
  __syncthreads();
  // distances and s_i = mean_j d_ij
  float sqi[4];
#pragma unroll
  for (int r = 0; r < 4; ++r) sqi[r] = sqv[16 * wave + q * 4 + r];
  float sp[4] = {0.f, 0.f, 0.f, 0.f};
#pragma unroll
  for (int nt = 0; nt < 8; ++nt) {
    float sqj = sqv[16 * nt + l16];
#pragma unroll
    for (int r = 0; r < 4; ++r) {
      float d2 = sqi[r] + sqj - 2.0f * g2[nt][r];
      sp[r] += sqrtf(fmaxf(d2, 0.f) + 1e-12f);
    }
  }
#pragma unroll
  for (int d = 1; d < 16; d <<= 1) {
#pragma unroll
    for (int r = 0; r < 4; ++r) { float t = sp[r]; t += __shfl_xor(t, d); sp[r] = t; }
  }
  if (l16 == 0) {
#pragma unroll
    for (int r = 0; r < 4; ++r) sm[16 * wave + q * 4 + r] = sp[r] * (1.0f / 128.0f);
  }
  __syncthreads();
  // softmax(s/TAU) by wave 0 (1/TAU = 4)
  if (wave == 0) {
    float l0 = sm[lane] * 4.0f;
    float l1 = sm[lane + 64] * 4.0f;
    float mx = fmaxf(l0, l1);
#pragma unroll
    for (int d = 1; d < 64; d <<= 1) mx = fmaxf(mx, __shfl_xor(mx, d));
    float e0 = __expf(l0 - mx), e1 = __expf(l1 - mx);
    float ss = e0 + e1;
#pragma unroll
    for (int d = 1; d < 64; d <<= 1) ss += __shfl_xor(ss, d);
    float inv = 1.0f / ss;
    float w0 = e0 * inv, w1 = e1 * inv;
    smw[lane] = w0;
    smw[lane + 64] = w1;
    out[131072 + g * 128 + lane] = w0;
    out[131072 + g * 128 + 64 + lane] = w1;
  }
  __syncthreads();
  // v_loc = sum_i w_i * Z[i,:]
  {
    int c = 16 * wave + l16;
    float acv = 0.f;
#pragma unroll
    for (int i0 = 0; i0 < 32; ++i0) {
      int i = q * 32 + i0;
      acv += smw[i] * bf2f(Zb[i * ZB_STRIDE + c]);
    }
    acv += __shfl_xor(acv, 16);
    acv += __shfl_xor(acv, 32);
    if (q == 0) out[g * 128 + c] = acv;
  }
}

// ---------------------------------------------------------------------------
extern "C" void kernel_launch(void* const* d_in, const int* in_sizes, int n_in,
                              void* d_out, int out_size, void* d_ws, size_t ws_size,
                              hipStream_t stream) {
  (void)in_sizes; (void)n_in; (void)out_size; (void)ws_size;
  const float* H        = (const float*)d_in[0];
  // d_in[1] = batch_ptr (uniform 128/graph, unused)
  const float* W_in     = (const float*)d_in[2];
  const float* b_in     = (const float*)d_in[3];
  const float* g_in     = (const float*)d_in[4];
  const float* beta_in  = (const float*)d_in[5];
  const float* Wb       = (const float*)d_in[6];
  const float* bb       = (const float*)d_in[7];
  const float* gb       = (const float*)d_in[8];
  const float* betab    = (const float*)d_in[9];
  const float* W_out    = (const float*)d_in[10];
  const float* b_out    = (const float*)d_in[11];
  const float* g_out    = (const float*)d_in[12];
  const float* beta_out = (const float*)d_in[13];
  float* out = (float*)d_out;
  unsigned short* ws = (unsigned short*)d_ws;
  unsigned short* Z = ws + 262144;      // 1024*128*128 bf16 = 33.5 MB

  prep_weights<<<120, 256, 0, stream>>>(W_in, Wb, W_out, ws);
  mlp_main<<<4096, 512, 0, stream>>>(H, ws, b_in, g_in, beta_in,
                                     bb, gb, betab, b_out, g_out, beta_out, Z);
  pool_main<<<1024, 512, 0, stream>>>(Z, out);
}